// Round 5
// baseline (245.830 us; speedup 1.0000x reference)
//
#include <hip/hip_runtime.h>

#define E_TOTAL  600000
#define N_NODES  100000
#define DFEAT    128
#define TPB_TILES 2
#define EPT      128                                // edges per tile
#define EPB      (EPT * TPB_TILES)                  // 256 edges per block
#define NB       ((E_TOTAL + EPB - 1) / EPB)        // 2344

typedef __attribute__((ext_vector_type(8))) short  short8;
typedef __attribute__((ext_vector_type(4))) float  f32x4;

static __device__ __forceinline__ unsigned short f2bf(float f) {
    unsigned int u = __float_as_uint(f);
    unsigned int r = (u + 0x7fffu + ((u >> 16) & 1u)) >> 16;
    return (unsigned short)r;
}
static __device__ __forceinline__ float bf2f(unsigned short u) {
    unsigned int x = ((unsigned int)u) << 16;
    return __uint_as_float(x);
}

// w1abt[c][k], c in [0,256): c<128 -> W1[k][c] (src half); c>=128 -> W1[128+k][c-128] (dst half)
// w2t[c][k] = W2[k][c]
__global__ void prep_w_fast(const float* __restrict__ W1, const float* __restrict__ W2,
                            unsigned short* __restrict__ w1abt, unsigned short* __restrict__ w2t) {
    int i = blockIdx.x * blockDim.x + threadIdx.x;
    if (i < 256 * 128) {
        int c = i >> 7, k = i & 127;
        w1abt[i] = f2bf(W1[(k + (c & 128)) * 128 + (c & 127)]);
    } else {
        int j = i - 256 * 128;
        if (j < 64 * 128) {
            int c = j >> 7, k = j & 127;
            w2t[j] = f2bf(W2[k * 64 + c]);
        }
    }
}

// PQ[n][0:128] = enc[n] @ W1a + b1 ; PQ[n][128:256] = enc[n] @ W1b   (bf16)
__global__ __launch_bounds__(256, 4) void build_pq(
        const float* __restrict__ enc, const float* __restrict__ b1,
        const unsigned short* __restrict__ w1abt, unsigned short* __restrict__ PQ)
{
    __shared__ unsigned short sX[64 * 128];     // swizzled bf16 enc tile (16 KB)

    const int tid = threadIdx.x, lane = tid & 63, w = tid >> 6;
    const int acol = lane & 15, g = lane >> 4;
    const int n0 = blockIdx.x * 64;

    {
        int r = tid >> 2, q = tid & 3;
        int n = n0 + r; if (n >= N_NODES) n = N_NODES - 1;
        const float* src = enc + (size_t)n * DFEAT + q * 32;
#pragma unroll
        for (int i = 0; i < 4; ++i) {
            float4 v0 = *reinterpret_cast<const float4*>(src + i * 8);
            float4 v1 = *reinterpret_cast<const float4*>(src + i * 8 + 4);
            short8 pv;
            pv[0] = (short)f2bf(v0.x); pv[1] = (short)f2bf(v0.y);
            pv[2] = (short)f2bf(v0.z); pv[3] = (short)f2bf(v0.w);
            pv[4] = (short)f2bf(v1.x); pv[5] = (short)f2bf(v1.y);
            pv[6] = (short)f2bf(v1.z); pv[7] = (short)f2bf(v1.w);
            int chunk = (q * 4 + i) ^ (r & 7);
            *reinterpret_cast<short8*>(&sX[r * 128 + chunk * 8]) = pv;
        }
    }
    float b1v[4];
#pragma unroll
    for (int ni = 0; ni < 4; ++ni) {
        int c = w * 64 + ni * 16 + acol;
        b1v[ni] = (c < 128) ? b1[c] : 0.f;
    }
    __syncthreads();

    f32x4 acc[4][4];
#pragma unroll
    for (int mi = 0; mi < 4; ++mi)
#pragma unroll
        for (int ni = 0; ni < 4; ++ni)
            acc[mi][ni] = (f32x4){0.f, 0.f, 0.f, 0.f};

#pragma unroll
    for (int ks = 0; ks < 4; ++ks) {
        short8 a[4];
#pragma unroll
        for (int mi = 0; mi < 4; ++mi) {
            int r = mi * 16 + acol;
            a[mi] = *reinterpret_cast<const short8*>(&sX[r * 128 + (((ks * 4 + g) ^ (r & 7)) * 8)]);
        }
#pragma unroll
        for (int ni = 0; ni < 4; ++ni) {
            int c = w * 64 + ni * 16 + acol;
            short8 bf = *reinterpret_cast<const short8*>(w1abt + c * 128 + ks * 32 + g * 8);
#pragma unroll
            for (int mi = 0; mi < 4; ++mi)
                acc[mi][ni] = __builtin_amdgcn_mfma_f32_16x16x32_bf16(a[mi], bf, acc[mi][ni], 0, 0, 0);
        }
    }

#pragma unroll
    for (int mi = 0; mi < 4; ++mi)
#pragma unroll
        for (int rr = 0; rr < 4; ++rr) {
            int n = n0 + mi * 16 + g * 4 + rr;
            if (n < N_NODES) {
                unsigned short* dst = PQ + (size_t)n * 256 + w * 64 + acol;
#pragma unroll
                for (int ni = 0; ni < 4; ++ni)
                    dst[ni * 16] = f2bf(acc[mi][ni][rr] + b1v[ni]);
            }
        }
}

// per-edge head: h1 = relu(P[src]+Q[dst]); h2 = relu(h1@W2+b2); logsoftmax(h2@W3+b3)
// R2-proven structure; only change: W2^T fragments read from L2 (no sW2 LDS stage),
// LDS 52->35 KB so 4 blocks (32 waves)/CU fit at VGPR<=64.
__global__ __launch_bounds__(512, 8) void edge_head(
        const unsigned short* __restrict__ PQ,
        const int* __restrict__ eidx,
        const unsigned short* __restrict__ w2t,
        const float* __restrict__ b2, const float* __restrict__ W3, const float* __restrict__ b3,
        float* __restrict__ out)
{
    __shared__ unsigned short sH1[128 * 128];   // swizzled bf16 h1 tile (32 KB)
    __shared__ float part[2][128][2];           // 2 KB

    const int tid = threadIdx.x, lane = tid & 63, w = tid >> 6;
    const int acol = lane & 15, g = lane >> 4;
    const int wm = w >> 1, wn = w & 1;          // 4x2 wave grid over [128 edges x 64 ch]
    const int le = tid >> 2, q = tid & 3;       // gather role

    float b2v[2], w3v[2][2];
#pragma unroll
    for (int ni = 0; ni < 2; ++ni) {
        int c = wn * 32 + ni * 16 + acol;
        b2v[ni] = b2[c];
        w3v[ni][0] = W3[c * 2]; w3v[ni][1] = W3[c * 2 + 1];
    }
    const float b3v0 = b3[0], b3v1 = b3[1];

    const int tile0 = blockIdx.x * TPB_TILES;
    short8 rp[4], rq[4];
    {   // prologue gather for first tile
        int e = tile0 * EPT + le; if (e >= E_TOTAL) e = E_TOTAL - 1;
        int sn = eidx[e], dn = eidx[E_TOTAL + e];
        const unsigned short* ps = PQ + (size_t)sn * 256 + q * 32;
        const unsigned short* pd = PQ + (size_t)dn * 256 + 128 + q * 32;
#pragma unroll
        for (int i = 0; i < 4; ++i) {
            rp[i] = *reinterpret_cast<const short8*>(ps + i * 8);
            rq[i] = *reinterpret_cast<const short8*>(pd + i * 8);
        }
    }

    for (int tl = 0; tl < TPB_TILES; ++tl) {
        const int tile = tile0 + tl;

        // h1 = relu(P+Q) -> bf16 swizzled into sH1
#pragma unroll
        for (int i = 0; i < 4; ++i) {
            short8 hv;
#pragma unroll
            for (int j = 0; j < 8; ++j) {
                float v = bf2f((unsigned short)rp[i][j]) + bf2f((unsigned short)rq[i][j]);
                v = fmaxf(v, 0.f);
                hv[j] = (short)f2bf(v);
            }
            int chunk = (q * 4 + i) ^ (le & 7);
            *reinterpret_cast<short8*>(&sH1[le * 128 + chunk * 8]) = hv;
        }

        // prefetch next tile's gather (hidden under GEMM2 + layer3)
        if (tl + 1 < TPB_TILES) {
            int e = (tile + 1) * EPT + le; if (e >= E_TOTAL) e = E_TOTAL - 1;
            int sn = eidx[e], dn = eidx[E_TOTAL + e];
            const unsigned short* ps = PQ + (size_t)sn * 256 + q * 32;
            const unsigned short* pd = PQ + (size_t)dn * 256 + 128 + q * 32;
#pragma unroll
            for (int i = 0; i < 4; ++i) {
                rp[i] = *reinterpret_cast<const short8*>(ps + i * 8);
                rq[i] = *reinterpret_cast<const short8*>(pd + i * 8);
            }
        }
        __syncthreads();   // barrier 1: sH1 ready

        // GEMM2: [128 x 128] @ [128 x 64]; W2^T fragments from L2
        f32x4 acc2[2][2];
#pragma unroll
        for (int mi = 0; mi < 2; ++mi)
#pragma unroll
            for (int ni = 0; ni < 2; ++ni)
                acc2[mi][ni] = (f32x4){0.f, 0.f, 0.f, 0.f};
#pragma unroll
        for (int ks = 0; ks < 4; ++ks) {
            short8 a2[2], bb[2];
#pragma unroll
            for (int mi = 0; mi < 2; ++mi) {
                int r = wm * 32 + mi * 16 + acol;
                a2[mi] = *reinterpret_cast<const short8*>(&sH1[r * 128 + (((ks * 4 + g) ^ (r & 7)) * 8)]);
            }
#pragma unroll
            for (int ni = 0; ni < 2; ++ni) {
                int c = wn * 32 + ni * 16 + acol;
                bb[ni] = *reinterpret_cast<const short8*>(w2t + c * 128 + ks * 32 + g * 8);
            }
#pragma unroll
            for (int mi = 0; mi < 2; ++mi)
#pragma unroll
                for (int ni = 0; ni < 2; ++ni)
                    acc2[mi][ni] = __builtin_amdgcn_mfma_f32_16x16x32_bf16(a2[mi], bb[ni], acc2[mi][ni], 0, 0, 0);
        }

        // layer3 partial logits in registers
        float p[8][2];
#pragma unroll
        for (int k = 0; k < 8; ++k) { p[k][0] = 0.f; p[k][1] = 0.f; }
#pragma unroll
        for (int mi = 0; mi < 2; ++mi)
#pragma unroll
            for (int ni = 0; ni < 2; ++ni)
#pragma unroll
                for (int rr = 0; rr < 4; ++rr) {
                    float h = acc2[mi][ni][rr] + b2v[ni];
                    h = fmaxf(h, 0.f);
                    p[mi * 4 + rr][0] = fmaf(h, w3v[ni][0], p[mi * 4 + rr][0]);
                    p[mi * 4 + rr][1] = fmaf(h, w3v[ni][1], p[mi * 4 + rr][1]);
                }
        // reduce over the 16 acol lanes
#pragma unroll
        for (int d = 1; d < 16; d <<= 1)
#pragma unroll
            for (int k = 0; k < 8; ++k) {
                p[k][0] += __shfl_xor(p[k][0], d, 64);
                p[k][1] += __shfl_xor(p[k][1], d, 64);
            }
        if (acol < 2) {
#pragma unroll
            for (int mi = 0; mi < 2; ++mi)
#pragma unroll
                for (int rr = 0; rr < 4; ++rr) {
                    int row = wm * 32 + mi * 16 + g * 4 + rr;
                    part[wn][row][acol] = p[mi * 4 + rr][acol];
                }
        }
        __syncthreads();   // barrier 2: part ready, sH1 free

        if (tid < 256) {
            int e = tid >> 1, c = tid & 1;
            float v = part[0][e][c] + part[1][e][c] + (c ? b3v1 : b3v0);
            float o = __shfl_xor(v, 1, 64);
            float m = fmaxf(v, o);
            float lse = m + __logf(__expf(v - m) + __expf(o - m));
            int ge = tile * EPT + e;
            if (ge < E_TOTAL) out[(size_t)ge * 2 + c] = v - lse;
        }
    }
}

// ============================ HOST ============================

extern "C" void kernel_launch(void* const* d_in, const int* in_sizes, int n_in,
                              void* d_out, int out_size, void* d_ws, size_t ws_size,
                              hipStream_t stream) {
    const float* enc = (const float*)d_in[0];
    const int*   eidx = (const int*)d_in[1];
    const float* W1 = (const float*)d_in[2];
    const float* b1 = (const float*)d_in[3];
    const float* W2 = (const float*)d_in[4];
    const float* b2 = (const float*)d_in[5];
    const float* W3 = (const float*)d_in[6];
    const float* b3 = (const float*)d_in[7];
    float* out = (float*)d_out;

    unsigned short* PQ    = (unsigned short*)d_ws;           // 100000*256 bf16 = 51.2 MB
    unsigned short* w1abt = PQ + (size_t)N_NODES * 256;      // 64 KB
    unsigned short* w2t   = w1abt + 256 * 128;               // 16 KB

    prep_w_fast<<<160, 256, 0, stream>>>(W1, W2, w1abt, w2t);
    build_pq<<<(N_NODES + 63) / 64, 256, 0, stream>>>(enc, b1, w1abt, PQ);
    edge_head<<<NB, 512, 0, stream>>>(PQ, eidx, w2t, b2, W3, b3, out);
}

// Round 6
// 150.678 us; speedup vs baseline: 1.6315x; 1.6315x over previous
//
#include <hip/hip_runtime.h>

#define E_TOTAL  600000
#define N_NODES  100000
#define DFEAT    128
#define TPB_TILES 2
#define EPT      128                                // edges per tile
#define EPB      (EPT * TPB_TILES)                  // 256 edges per block
#define NB       ((E_TOTAL + EPB - 1) / EPB)        // 2344

typedef __attribute__((ext_vector_type(8))) short  short8;
typedef __attribute__((ext_vector_type(4))) float  f32x4;

static __device__ __forceinline__ unsigned short f2bf(float f) {
    unsigned int u = __float_as_uint(f);
    unsigned int r = (u + 0x7fffu + ((u >> 16) & 1u)) >> 16;
    return (unsigned short)r;
}
static __device__ __forceinline__ float bf2f(unsigned short u) {
    unsigned int x = ((unsigned int)u) << 16;
    return __uint_as_float(x);
}

// w1abt[c][k], c in [0,256): c<128 -> W1[k][c] (src half); c>=128 -> W1[128+k][c-128] (dst half)
// w2t[c][k] = W2[k][c]
__global__ void prep_w_fast(const float* __restrict__ W1, const float* __restrict__ W2,
                            unsigned short* __restrict__ w1abt, unsigned short* __restrict__ w2t) {
    int i = blockIdx.x * blockDim.x + threadIdx.x;
    if (i < 256 * 128) {
        int c = i >> 7, k = i & 127;
        w1abt[i] = f2bf(W1[(k + (c & 128)) * 128 + (c & 127)]);
    } else {
        int j = i - 256 * 128;
        if (j < 64 * 128) {
            int c = j >> 7, k = j & 127;
            w2t[j] = f2bf(W2[k * 64 + c]);
        }
    }
}

// PQ[n][0:128] = enc[n] @ W1a + b1 ; PQ[n][128:256] = enc[n] @ W1b   (bf16)
__global__ __launch_bounds__(256, 4) void build_pq(
        const float* __restrict__ enc, const float* __restrict__ b1,
        const unsigned short* __restrict__ w1abt, unsigned short* __restrict__ PQ)
{
    __shared__ unsigned short sX[64 * 128];     // swizzled bf16 enc tile (16 KB)

    const int tid = threadIdx.x, lane = tid & 63, w = tid >> 6;
    const int acol = lane & 15, g = lane >> 4;
    const int n0 = blockIdx.x * 64;

    {
        int r = tid >> 2, q = tid & 3;
        int n = n0 + r; if (n >= N_NODES) n = N_NODES - 1;
        const float* src = enc + (size_t)n * DFEAT + q * 32;
#pragma unroll
        for (int i = 0; i < 4; ++i) {
            float4 v0 = *reinterpret_cast<const float4*>(src + i * 8);
            float4 v1 = *reinterpret_cast<const float4*>(src + i * 8 + 4);
            short8 pv;
            pv[0] = (short)f2bf(v0.x); pv[1] = (short)f2bf(v0.y);
            pv[2] = (short)f2bf(v0.z); pv[3] = (short)f2bf(v0.w);
            pv[4] = (short)f2bf(v1.x); pv[5] = (short)f2bf(v1.y);
            pv[6] = (short)f2bf(v1.z); pv[7] = (short)f2bf(v1.w);
            int chunk = (q * 4 + i) ^ (r & 7);
            *reinterpret_cast<short8*>(&sX[r * 128 + chunk * 8]) = pv;
        }
    }
    float b1v[4];
#pragma unroll
    for (int ni = 0; ni < 4; ++ni) {
        int c = w * 64 + ni * 16 + acol;
        b1v[ni] = (c < 128) ? b1[c] : 0.f;
    }
    __syncthreads();

    f32x4 acc[4][4];
#pragma unroll
    for (int mi = 0; mi < 4; ++mi)
#pragma unroll
        for (int ni = 0; ni < 4; ++ni)
            acc[mi][ni] = (f32x4){0.f, 0.f, 0.f, 0.f};

#pragma unroll
    for (int ks = 0; ks < 4; ++ks) {
        short8 a[4];
#pragma unroll
        for (int mi = 0; mi < 4; ++mi) {
            int r = mi * 16 + acol;
            a[mi] = *reinterpret_cast<const short8*>(&sX[r * 128 + (((ks * 4 + g) ^ (r & 7)) * 8)]);
        }
#pragma unroll
        for (int ni = 0; ni < 4; ++ni) {
            int c = w * 64 + ni * 16 + acol;
            short8 bf = *reinterpret_cast<const short8*>(w1abt + c * 128 + ks * 32 + g * 8);
#pragma unroll
            for (int mi = 0; mi < 4; ++mi)
                acc[mi][ni] = __builtin_amdgcn_mfma_f32_16x16x32_bf16(a[mi], bf, acc[mi][ni], 0, 0, 0);
        }
    }

#pragma unroll
    for (int mi = 0; mi < 4; ++mi)
#pragma unroll
        for (int rr = 0; rr < 4; ++rr) {
            int n = n0 + mi * 16 + g * 4 + rr;
            if (n < N_NODES) {
                unsigned short* dst = PQ + (size_t)n * 256 + w * 64 + acol;
#pragma unroll
                for (int ni = 0; ni < 4; ++ni)
                    dst[ni * 16] = f2bf(acc[mi][ni][rr] + b1v[ni]);
            }
        }
}

// per-edge head: h1 = relu(P[src]+Q[dst]); h2 = relu(h1@W2+b2); logsoftmax(h2@W3+b3)
// R2-proven structure + W2^T from L2 (no sW2 stage). launch_bounds(512,4):
// VGPR cap 128 (R2 measured 60, no spill); LDS 34.8 KB -> up to 4 blocks/CU.
__global__ __launch_bounds__(512, 4) void edge_head(
        const unsigned short* __restrict__ PQ,
        const int* __restrict__ eidx,
        const unsigned short* __restrict__ w2t,
        const float* __restrict__ b2, const float* __restrict__ W3, const float* __restrict__ b3,
        float* __restrict__ out)
{
    __shared__ unsigned short sH1[128 * 128];   // swizzled bf16 h1 tile (32 KB)
    __shared__ float part[2][128][2];           // 2 KB

    const int tid = threadIdx.x, lane = tid & 63, w = tid >> 6;
    const int acol = lane & 15, g = lane >> 4;
    const int wm = w >> 1, wn = w & 1;          // 4x2 wave grid over [128 edges x 64 ch]
    const int le = tid >> 2, q = tid & 3;       // gather role

    float b2v[2], w3v[2][2];
#pragma unroll
    for (int ni = 0; ni < 2; ++ni) {
        int c = wn * 32 + ni * 16 + acol;
        b2v[ni] = b2[c];
        w3v[ni][0] = W3[c * 2]; w3v[ni][1] = W3[c * 2 + 1];
    }
    const float b3v0 = b3[0], b3v1 = b3[1];

    const int tile0 = blockIdx.x * TPB_TILES;
    short8 rp[4], rq[4];
    {   // prologue gather for first tile
        int e = tile0 * EPT + le; if (e >= E_TOTAL) e = E_TOTAL - 1;
        int sn = eidx[e], dn = eidx[E_TOTAL + e];
        const unsigned short* ps = PQ + (size_t)sn * 256 + q * 32;
        const unsigned short* pd = PQ + (size_t)dn * 256 + 128 + q * 32;
#pragma unroll
        for (int i = 0; i < 4; ++i) {
            rp[i] = *reinterpret_cast<const short8*>(ps + i * 8);
            rq[i] = *reinterpret_cast<const short8*>(pd + i * 8);
        }
    }

    for (int tl = 0; tl < TPB_TILES; ++tl) {
        const int tile = tile0 + tl;

        // h1 = relu(P+Q) -> bf16 swizzled into sH1
#pragma unroll
        for (int i = 0; i < 4; ++i) {
            short8 hv;
#pragma unroll
            for (int j = 0; j < 8; ++j) {
                float v = bf2f((unsigned short)rp[i][j]) + bf2f((unsigned short)rq[i][j]);
                v = fmaxf(v, 0.f);
                hv[j] = (short)f2bf(v);
            }
            int chunk = (q * 4 + i) ^ (le & 7);
            *reinterpret_cast<short8*>(&sH1[le * 128 + chunk * 8]) = hv;
        }

        // prefetch next tile's gather (hidden under GEMM2 + layer3)
        if (tl + 1 < TPB_TILES) {
            int e = (tile + 1) * EPT + le; if (e >= E_TOTAL) e = E_TOTAL - 1;
            int sn = eidx[e], dn = eidx[E_TOTAL + e];
            const unsigned short* ps = PQ + (size_t)sn * 256 + q * 32;
            const unsigned short* pd = PQ + (size_t)dn * 256 + 128 + q * 32;
#pragma unroll
            for (int i = 0; i < 4; ++i) {
                rp[i] = *reinterpret_cast<const short8*>(ps + i * 8);
                rq[i] = *reinterpret_cast<const short8*>(pd + i * 8);
            }
        }
        __syncthreads();   // barrier 1: sH1 ready

        // GEMM2: [128 x 128] @ [128 x 64]; W2^T fragments from L2
        f32x4 acc2[2][2];
#pragma unroll
        for (int mi = 0; mi < 2; ++mi)
#pragma unroll
            for (int ni = 0; ni < 2; ++ni)
                acc2[mi][ni] = (f32x4){0.f, 0.f, 0.f, 0.f};
#pragma unroll
        for (int ks = 0; ks < 4; ++ks) {
            short8 a2[2], bb[2];
#pragma unroll
            for (int mi = 0; mi < 2; ++mi) {
                int r = wm * 32 + mi * 16 + acol;
                a2[mi] = *reinterpret_cast<const short8*>(&sH1[r * 128 + (((ks * 4 + g) ^ (r & 7)) * 8)]);
            }
#pragma unroll
            for (int ni = 0; ni < 2; ++ni) {
                int c = wn * 32 + ni * 16 + acol;
                bb[ni] = *reinterpret_cast<const short8*>(w2t + c * 128 + ks * 32 + g * 8);
            }
#pragma unroll
            for (int mi = 0; mi < 2; ++mi)
#pragma unroll
                for (int ni = 0; ni < 2; ++ni)
                    acc2[mi][ni] = __builtin_amdgcn_mfma_f32_16x16x32_bf16(a2[mi], bb[ni], acc2[mi][ni], 0, 0, 0);
        }

        // layer3 partial logits in registers
        float p[8][2];
#pragma unroll
        for (int k = 0; k < 8; ++k) { p[k][0] = 0.f; p[k][1] = 0.f; }
#pragma unroll
        for (int mi = 0; mi < 2; ++mi)
#pragma unroll
            for (int ni = 0; ni < 2; ++ni)
#pragma unroll
                for (int rr = 0; rr < 4; ++rr) {
                    float h = acc2[mi][ni][rr] + b2v[ni];
                    h = fmaxf(h, 0.f);
                    p[mi * 4 + rr][0] = fmaf(h, w3v[ni][0], p[mi * 4 + rr][0]);
                    p[mi * 4 + rr][1] = fmaf(h, w3v[ni][1], p[mi * 4 + rr][1]);
                }
        // reduce over the 16 acol lanes
#pragma unroll
        for (int d = 1; d < 16; d <<= 1)
#pragma unroll
            for (int k = 0; k < 8; ++k) {
                p[k][0] += __shfl_xor(p[k][0], d, 64);
                p[k][1] += __shfl_xor(p[k][1], d, 64);
            }
        if (acol < 2) {
#pragma unroll
            for (int mi = 0; mi < 2; ++mi)
#pragma unroll
                for (int rr = 0; rr < 4; ++rr) {
                    int row = wm * 32 + mi * 16 + g * 4 + rr;
                    part[wn][row][acol] = p[mi * 4 + rr][acol];
                }
        }
        __syncthreads();   // barrier 2: part ready, sH1 free

        if (tid < 256) {
            int e = tid >> 1, c = tid & 1;
            float v = part[0][e][c] + part[1][e][c] + (c ? b3v1 : b3v0);
            float o = __shfl_xor(v, 1, 64);
            float m = fmaxf(v, o);
            float lse = m + __logf(__expf(v - m) + __expf(o - m));
            int ge = tile * EPT + e;
            if (ge < E_TOTAL) out[(size_t)ge * 2 + c] = v - lse;
        }
    }
}

// ============================ HOST ============================

extern "C" void kernel_launch(void* const* d_in, const int* in_sizes, int n_in,
                              void* d_out, int out_size, void* d_ws, size_t ws_size,
                              hipStream_t stream) {
    const float* enc = (const float*)d_in[0];
    const int*   eidx = (const int*)d_in[1];
    const float* W1 = (const float*)d_in[2];
    const float* b1 = (const float*)d_in[3];
    const float* W2 = (const float*)d_in[4];
    const float* b2 = (const float*)d_in[5];
    const float* W3 = (const float*)d_in[6];
    const float* b3 = (const float*)d_in[7];
    float* out = (float*)d_out;

    unsigned short* PQ    = (unsigned short*)d_ws;           // 100000*256 bf16 = 51.2 MB
    unsigned short* w1abt = PQ + (size_t)N_NODES * 256;      // 64 KB
    unsigned short* w2t   = w1abt + 256 * 128;               // 16 KB

    prep_w_fast<<<160, 256, 0, stream>>>(W1, W2, w1abt, w2t);
    build_pq<<<(N_NODES + 63) / 64, 256, 0, stream>>>(enc, b1, w1abt, PQ);
    edge_head<<<NB, 512, 0, stream>>>(PQ, eidx, w2t, b2, W3, b3, out);
}

// Round 7
// 87.266 us; speedup vs baseline: 2.8170x; 1.7266x over previous
//
#include <hip/hip_runtime.h>

#define E_TOTAL  600000
#define N_NODES  100000
#define DFEAT    128
#define TPB_TILES 2
#define EPT      128                                // edges per tile
#define EPB      (EPT * TPB_TILES)                  // 256 edges per block
#define NB       ((E_TOTAL + EPB - 1) / EPB)        // 2344

typedef __attribute__((ext_vector_type(8))) short  short8;
typedef __attribute__((ext_vector_type(4))) float  f32x4;

static __device__ __forceinline__ unsigned short f2bf(float f) {
    unsigned int u = __float_as_uint(f);
    unsigned int r = (u + 0x7fffu + ((u >> 16) & 1u)) >> 16;
    return (unsigned short)r;
}
static __device__ __forceinline__ float bf2f(unsigned short u) {
    unsigned int x = ((unsigned int)u) << 16;
    return __uint_as_float(x);
}

// w1abt[c][k], c in [0,256): c<128 -> W1[k][c] (src half); c>=128 -> W1[128+k][c-128] (dst half)
// w2t[c][k] = W2[k][c]
__global__ void prep_w_fast(const float* __restrict__ W1, const float* __restrict__ W2,
                            unsigned short* __restrict__ w1abt, unsigned short* __restrict__ w2t) {
    int i = blockIdx.x * blockDim.x + threadIdx.x;
    if (i < 256 * 128) {
        int c = i >> 7, k = i & 127;
        w1abt[i] = f2bf(W1[(k + (c & 128)) * 128 + (c & 127)]);
    } else {
        int j = i - 256 * 128;
        if (j < 64 * 128) {
            int c = j >> 7, k = j & 127;
            w2t[j] = f2bf(W2[k * 64 + c]);
        }
    }
}

// PQ[n][0:128] = enc[n] @ W1a + b1 ; PQ[n][128:256] = enc[n] @ W1b   (bf16)
__global__ __launch_bounds__(256, 4) void build_pq(
        const float* __restrict__ enc, const float* __restrict__ b1,
        const unsigned short* __restrict__ w1abt, unsigned short* __restrict__ PQ)
{
    __shared__ unsigned short sX[64 * 128];     // swizzled bf16 enc tile (16 KB)

    const int tid = threadIdx.x, lane = tid & 63, w = tid >> 6;
    const int acol = lane & 15, g = lane >> 4;
    const int n0 = blockIdx.x * 64;

    {
        int r = tid >> 2, q = tid & 3;
        int n = n0 + r; if (n >= N_NODES) n = N_NODES - 1;
        const float* src = enc + (size_t)n * DFEAT + q * 32;
#pragma unroll
        for (int i = 0; i < 4; ++i) {
            float4 v0 = *reinterpret_cast<const float4*>(src + i * 8);
            float4 v1 = *reinterpret_cast<const float4*>(src + i * 8 + 4);
            short8 pv;
            pv[0] = (short)f2bf(v0.x); pv[1] = (short)f2bf(v0.y);
            pv[2] = (short)f2bf(v0.z); pv[3] = (short)f2bf(v0.w);
            pv[4] = (short)f2bf(v1.x); pv[5] = (short)f2bf(v1.y);
            pv[6] = (short)f2bf(v1.z); pv[7] = (short)f2bf(v1.w);
            int chunk = (q * 4 + i) ^ (r & 7);
            *reinterpret_cast<short8*>(&sX[r * 128 + chunk * 8]) = pv;
        }
    }
    float b1v[4];
#pragma unroll
    for (int ni = 0; ni < 4; ++ni) {
        int c = w * 64 + ni * 16 + acol;
        b1v[ni] = (c < 128) ? b1[c] : 0.f;
    }
    __syncthreads();

    f32x4 acc[4][4];
#pragma unroll
    for (int mi = 0; mi < 4; ++mi)
#pragma unroll
        for (int ni = 0; ni < 4; ++ni)
            acc[mi][ni] = (f32x4){0.f, 0.f, 0.f, 0.f};

#pragma unroll
    for (int ks = 0; ks < 4; ++ks) {
        short8 a[4];
#pragma unroll
        for (int mi = 0; mi < 4; ++mi) {
            int r = mi * 16 + acol;
            a[mi] = *reinterpret_cast<const short8*>(&sX[r * 128 + (((ks * 4 + g) ^ (r & 7)) * 8)]);
        }
#pragma unroll
        for (int ni = 0; ni < 4; ++ni) {
            int c = w * 64 + ni * 16 + acol;
            short8 bf = *reinterpret_cast<const short8*>(w1abt + c * 128 + ks * 32 + g * 8);
#pragma unroll
            for (int mi = 0; mi < 4; ++mi)
                acc[mi][ni] = __builtin_amdgcn_mfma_f32_16x16x32_bf16(a[mi], bf, acc[mi][ni], 0, 0, 0);
        }
    }

#pragma unroll
    for (int mi = 0; mi < 4; ++mi)
#pragma unroll
        for (int rr = 0; rr < 4; ++rr) {
            int n = n0 + mi * 16 + g * 4 + rr;
            if (n < N_NODES) {
                unsigned short* dst = PQ + (size_t)n * 256 + w * 64 + acol;
#pragma unroll
                for (int ni = 0; ni < 4; ++ni)
                    dst[ni * 16] = f2bf(acc[mi][ni][rr] + b1v[ni]);
            }
        }
}

// per-edge head: h1 = relu(P[src]+Q[dst]); h2 = relu(h1@W2+b2); logsoftmax(h2@W3+b3)
// R2 gather/staging structure + swapped-operand GEMM2 (D[ch][edge]):
// all 64 h2 channels of an edge live in one wave -> layer3 = 48 fma + 2 shfl,
// no part[] LDS, no butterfly. sW2 staged in LDS (L2 is thrashed by gather stream).
__global__ __launch_bounds__(512, 4) void edge_head(
        const unsigned short* __restrict__ PQ,
        const int* __restrict__ eidx,
        const unsigned short* __restrict__ w2t,
        const float* __restrict__ b2, const float* __restrict__ W3, const float* __restrict__ b3,
        float* __restrict__ out)
{
    __shared__ unsigned short sH1[128 * 128];   // swizzled bf16 h1 tile (32 KB)
    __shared__ unsigned short sW2[64 * 128];    // swizzled W2^T (16 KB)
    __shared__ float sB2[64];
    __shared__ float sW3[128];

    const int tid = threadIdx.x, lane = tid & 63, w = tid >> 6;
    const int e16 = lane & 15, g = lane >> 4;
    const int le = tid >> 2, q = tid & 3;       // gather role

    // stage W2^T swizzled + b2/W3
    {
        int c = tid >> 3, s = tid & 7;
#pragma unroll
        for (int h = 0; h < 2; ++h) {
            int cs = s + h * 8;
            short8 v = *reinterpret_cast<const short8*>(w2t + c * 128 + cs * 8);
            *reinterpret_cast<short8*>(&sW2[c * 128 + ((cs ^ (c & 7)) * 8)]) = v;
        }
    }
    if (tid < 64)       sB2[tid] = b2[tid];
    else if (tid < 192) sW3[tid - 64] = W3[tid - 64];
    const float b3v0 = b3[0], b3v1 = b3[1];

    const int tile0 = blockIdx.x * TPB_TILES;
    short8 rp[4], rq[4];
    {   // prologue gather for first tile (coalesced: 4 threads cover one 256B half-row)
        int e = tile0 * EPT + le; if (e >= E_TOTAL) e = E_TOTAL - 1;
        int sn = eidx[e], dn = eidx[E_TOTAL + e];
        const unsigned short* ps = PQ + (size_t)sn * 256 + q * 32;
        const unsigned short* pd = PQ + (size_t)dn * 256 + 128 + q * 32;
#pragma unroll
        for (int i = 0; i < 4; ++i) {
            rp[i] = *reinterpret_cast<const short8*>(ps + i * 8);
            rq[i] = *reinterpret_cast<const short8*>(pd + i * 8);
        }
    }

    for (int tl = 0; tl < TPB_TILES; ++tl) {
        const int tile = tile0 + tl;

        // h1 = relu(P+Q) -> bf16 swizzled into sH1
#pragma unroll
        for (int i = 0; i < 4; ++i) {
            short8 hv;
#pragma unroll
            for (int j = 0; j < 8; ++j) {
                float v = bf2f((unsigned short)rp[i][j]) + bf2f((unsigned short)rq[i][j]);
                v = fmaxf(v, 0.f);
                hv[j] = (short)f2bf(v);
            }
            int chunk = (q * 4 + i) ^ (le & 7);
            *reinterpret_cast<short8*>(&sH1[le * 128 + chunk * 8]) = hv;
        }

        // prefetch next tile's gather (hidden under GEMM2 + layer3)
        if (tl + 1 < TPB_TILES) {
            int e = (tile + 1) * EPT + le; if (e >= E_TOTAL) e = E_TOTAL - 1;
            int sn = eidx[e], dn = eidx[E_TOTAL + e];
            const unsigned short* ps = PQ + (size_t)sn * 256 + q * 32;
            const unsigned short* pd = PQ + (size_t)dn * 256 + 128 + q * 32;
#pragma unroll
            for (int i = 0; i < 4; ++i) {
                rp[i] = *reinterpret_cast<const short8*>(ps + i * 8);
                rq[i] = *reinterpret_cast<const short8*>(pd + i * 8);
            }
        }
        __syncthreads();   // barrier 1: sH1 ready (and, on tile 0, sW2/sB2/sW3 ready)

        // GEMM2 swapped: D[ch][edge] = W2^T @ h1^T; wave w owns edges w*16..w*16+15
        const int hrow = w * 16 + e16;            // this lane's edge row in sH1
        f32x4 acc[4];
#pragma unroll
        for (int t = 0; t < 4; ++t) acc[t] = (f32x4){0.f, 0.f, 0.f, 0.f};
#pragma unroll
        for (int ks = 0; ks < 4; ++ks) {
            short8 hb = *reinterpret_cast<const short8*>(
                &sH1[hrow * 128 + (((ks * 4 + g) ^ (hrow & 7)) * 8)]);
#pragma unroll
            for (int t = 0; t < 4; ++t) {
                int ch = t * 16 + e16;
                short8 av = *reinterpret_cast<const short8*>(
                    &sW2[ch * 128 + (((ks * 4 + g) ^ (ch & 7)) * 8)]);
                acc[t] = __builtin_amdgcn_mfma_f32_16x16x32_bf16(av, hb, acc[t], 0, 0, 0);
            }
        }

        // layer 3: lane holds ch = t*16 + g*4 + rr for edge hrow
        float lg0 = 0.f, lg1 = 0.f;
#pragma unroll
        for (int t = 0; t < 4; ++t) {
            int c0 = t * 16 + g * 4;
            float4 bb  = *reinterpret_cast<const float4*>(&sB2[c0]);
            float4 w30 = *reinterpret_cast<const float4*>(&sW3[c0 * 2]);
            float4 w31 = *reinterpret_cast<const float4*>(&sW3[c0 * 2 + 4]);
            float h0 = fmaxf(acc[t][0] + bb.x, 0.f);
            float h1 = fmaxf(acc[t][1] + bb.y, 0.f);
            float h2 = fmaxf(acc[t][2] + bb.z, 0.f);
            float h3 = fmaxf(acc[t][3] + bb.w, 0.f);
            lg0 = fmaf(h0, w30.x, lg0); lg1 = fmaf(h0, w30.y, lg1);
            lg0 = fmaf(h1, w30.z, lg0); lg1 = fmaf(h1, w30.w, lg1);
            lg0 = fmaf(h2, w31.x, lg0); lg1 = fmaf(h2, w31.y, lg1);
            lg0 = fmaf(h3, w31.z, lg0); lg1 = fmaf(h3, w31.w, lg1);
        }
        // reduce over the 4 k-groups (lanes e16, e16+16, e16+32, e16+48)
        lg0 += __shfl_xor(lg0, 16, 64); lg1 += __shfl_xor(lg1, 16, 64);
        lg0 += __shfl_xor(lg0, 32, 64); lg1 += __shfl_xor(lg1, 32, 64);

        int ge = tile * EPT + hrow;
        if (g == 0 && ge < E_TOTAL) {
            float v0 = lg0 + b3v0, v1 = lg1 + b3v1;
            float m = fmaxf(v0, v1);
            float lse = m + __logf(__expf(v0 - m) + __expf(v1 - m));
            *reinterpret_cast<float2*>(out + (size_t)ge * 2) = make_float2(v0 - lse, v1 - lse);
        }
        __syncthreads();   // barrier 2: sH1 reads done before next tile's overwrite
    }
}

// ============================ HOST ============================

extern "C" void kernel_launch(void* const* d_in, const int* in_sizes, int n_in,
                              void* d_out, int out_size, void* d_ws, size_t ws_size,
                              hipStream_t stream) {
    const float* enc = (const float*)d_in[0];
    const int*   eidx = (const int*)d_in[1];
    const float* W1 = (const float*)d_in[2];
    const float* b1 = (const float*)d_in[3];
    const float* W2 = (const float*)d_in[4];
    const float* b2 = (const float*)d_in[5];
    const float* W3 = (const float*)d_in[6];
    const float* b3 = (const float*)d_in[7];
    float* out = (float*)d_out;

    unsigned short* PQ    = (unsigned short*)d_ws;           // 100000*256 bf16 = 51.2 MB
    unsigned short* w1abt = PQ + (size_t)N_NODES * 256;      // 64 KB
    unsigned short* w2t   = w1abt + 256 * 128;               // 16 KB

    prep_w_fast<<<160, 256, 0, stream>>>(W1, W2, w1abt, w2t);
    build_pq<<<(N_NODES + 63) / 64, 256, 0, stream>>>(enc, b1, w1abt, PQ);
    edge_head<<<NB, 512, 0, stream>>>(PQ, eidx, w2t, b2, W3, b3, out);
}

// Round 8
// 86.428 us; speedup vs baseline: 2.8443x; 1.0097x over previous
//
#include <hip/hip_runtime.h>
#include <hip/hip_fp16.h>

#define E_TOTAL  600000
#define N_NODES  100000
#define DFEAT    128
#define TPB_TILES 2
#define EPT      128                                // edges per tile
#define EPB      (EPT * TPB_TILES)                  // 256 edges per block
#define NB       ((E_TOTAL + EPB - 1) / EPB)        // 2344

typedef __attribute__((ext_vector_type(8))) short     short8;
typedef __attribute__((ext_vector_type(8))) _Float16  half8;
typedef __attribute__((ext_vector_type(4))) float     f32x4;

static __device__ __forceinline__ unsigned short f2h(float f) {
    _Float16 h = (_Float16)f;
    return __builtin_bit_cast(unsigned short, h);
}

static __device__ __forceinline__ f32x4 mfma_f16(short8 a, short8 b, f32x4 c) {
    return __builtin_amdgcn_mfma_f32_16x16x32_f16(
        __builtin_bit_cast(half8, a), __builtin_bit_cast(half8, b), c, 0, 0, 0);
}

// packed f16: relu(a + b), 4x v_pk_add_f16 + 4x v_pk_max_f16
static __device__ __forceinline__ short8 h8_add_relu(short8 a, short8 b) {
    half8 s = __builtin_bit_cast(half8, a) + __builtin_bit_cast(half8, b);
    half8 z = {};
    s = __builtin_elementwise_max(s, z);
    return __builtin_bit_cast(short8, s);
}

// w1abt[c][k] (f16), c in [0,256): c<128 -> W1[k][c] (src half); c>=128 -> W1[128+k][c-128]
// w2t[c][k] (f16) = W2[k][c]
__global__ void prep_w_fast(const float* __restrict__ W1, const float* __restrict__ W2,
                            unsigned short* __restrict__ w1abt, unsigned short* __restrict__ w2t) {
    int i = blockIdx.x * blockDim.x + threadIdx.x;
    if (i < 256 * 128) {
        int c = i >> 7, k = i & 127;
        w1abt[i] = f2h(W1[(k + (c & 128)) * 128 + (c & 127)]);
    } else {
        int j = i - 256 * 128;
        if (j < 64 * 128) {
            int c = j >> 7, k = j & 127;
            w2t[j] = f2h(W2[k * 64 + c]);
        }
    }
}

// PQ[n][0:128] = enc[n] @ W1a + b1 ; PQ[n][128:256] = enc[n] @ W1b   (f16)
__global__ __launch_bounds__(256, 4) void build_pq(
        const float* __restrict__ enc, const float* __restrict__ b1,
        const unsigned short* __restrict__ w1abt, unsigned short* __restrict__ PQ)
{
    __shared__ unsigned short sX[64 * 128];     // swizzled f16 enc tile (16 KB)

    const int tid = threadIdx.x, lane = tid & 63, w = tid >> 6;
    const int acol = lane & 15, g = lane >> 4;
    const int n0 = blockIdx.x * 64;

    {
        int r = tid >> 2, q = tid & 3;
        int n = n0 + r; if (n >= N_NODES) n = N_NODES - 1;
        const float* src = enc + (size_t)n * DFEAT + q * 32;
#pragma unroll
        for (int i = 0; i < 4; ++i) {
            float4 v0 = *reinterpret_cast<const float4*>(src + i * 8);
            float4 v1 = *reinterpret_cast<const float4*>(src + i * 8 + 4);
            short8 pv;
            pv[0] = (short)f2h(v0.x); pv[1] = (short)f2h(v0.y);
            pv[2] = (short)f2h(v0.z); pv[3] = (short)f2h(v0.w);
            pv[4] = (short)f2h(v1.x); pv[5] = (short)f2h(v1.y);
            pv[6] = (short)f2h(v1.z); pv[7] = (short)f2h(v1.w);
            int chunk = (q * 4 + i) ^ (r & 7);
            *reinterpret_cast<short8*>(&sX[r * 128 + chunk * 8]) = pv;
        }
    }
    float b1v[4];
#pragma unroll
    for (int ni = 0; ni < 4; ++ni) {
        int c = w * 64 + ni * 16 + acol;
        b1v[ni] = (c < 128) ? b1[c] : 0.f;
    }
    __syncthreads();

    f32x4 acc[4][4];
#pragma unroll
    for (int mi = 0; mi < 4; ++mi)
#pragma unroll
        for (int ni = 0; ni < 4; ++ni)
            acc[mi][ni] = (f32x4){0.f, 0.f, 0.f, 0.f};

#pragma unroll
    for (int ks = 0; ks < 4; ++ks) {
        short8 a[4];
#pragma unroll
        for (int mi = 0; mi < 4; ++mi) {
            int r = mi * 16 + acol;
            a[mi] = *reinterpret_cast<const short8*>(&sX[r * 128 + (((ks * 4 + g) ^ (r & 7)) * 8)]);
        }
#pragma unroll
        for (int ni = 0; ni < 4; ++ni) {
            int c = w * 64 + ni * 16 + acol;
            short8 bf = *reinterpret_cast<const short8*>(w1abt + c * 128 + ks * 32 + g * 8);
#pragma unroll
            for (int mi = 0; mi < 4; ++mi)
                acc[mi][ni] = mfma_f16(a[mi], bf, acc[mi][ni]);
        }
    }

#pragma unroll
    for (int mi = 0; mi < 4; ++mi)
#pragma unroll
        for (int rr = 0; rr < 4; ++rr) {
            int n = n0 + mi * 16 + g * 4 + rr;
            if (n < N_NODES) {
                unsigned short* dst = PQ + (size_t)n * 256 + w * 64 + acol;
#pragma unroll
                for (int ni = 0; ni < 4; ++ni)
                    dst[ni * 16] = f2h(acc[mi][ni][rr] + b1v[ni]);
            }
        }
}

// per-edge head: h1 = relu(P[src]+Q[dst]) in packed f16; h2^T = W2^T @ h1^T (swapped MFMA);
// layer3 + log_softmax in-wave (48 fma + 2 shfl). Structure identical to R7.
__global__ __launch_bounds__(512, 4) void edge_head(
        const unsigned short* __restrict__ PQ,
        const int* __restrict__ eidx,
        const unsigned short* __restrict__ w2t,
        const float* __restrict__ b2, const float* __restrict__ W3, const float* __restrict__ b3,
        float* __restrict__ out)
{
    __shared__ unsigned short sH1[128 * 128];   // swizzled f16 h1 tile (32 KB)
    __shared__ unsigned short sW2[64 * 128];    // swizzled W2^T f16 (16 KB)
    __shared__ float sB2[64];
    __shared__ float sW3[128];

    const int tid = threadIdx.x, lane = tid & 63, w = tid >> 6;
    const int e16 = lane & 15, g = lane >> 4;
    const int le = tid >> 2, q = tid & 3;       // gather role

    // stage W2^T swizzled + b2/W3
    {
        int c = tid >> 3, s = tid & 7;
#pragma unroll
        for (int h = 0; h < 2; ++h) {
            int cs = s + h * 8;
            short8 v = *reinterpret_cast<const short8*>(w2t + c * 128 + cs * 8);
            *reinterpret_cast<short8*>(&sW2[c * 128 + ((cs ^ (c & 7)) * 8)]) = v;
        }
    }
    if (tid < 64)       sB2[tid] = b2[tid];
    else if (tid < 192) sW3[tid - 64] = W3[tid - 64];
    const float b3v0 = b3[0], b3v1 = b3[1];

    const int tile0 = blockIdx.x * TPB_TILES;
    short8 rp[4], rq[4];
    {   // prologue gather for first tile (coalesced: 4 threads cover one 256B half-row)
        int e = tile0 * EPT + le; if (e >= E_TOTAL) e = E_TOTAL - 1;
        int sn = eidx[e], dn = eidx[E_TOTAL + e];
        const unsigned short* ps = PQ + (size_t)sn * 256 + q * 32;
        const unsigned short* pd = PQ + (size_t)dn * 256 + 128 + q * 32;
#pragma unroll
        for (int i = 0; i < 4; ++i) {
            rp[i] = *reinterpret_cast<const short8*>(ps + i * 8);
            rq[i] = *reinterpret_cast<const short8*>(pd + i * 8);
        }
    }

    for (int tl = 0; tl < TPB_TILES; ++tl) {
        const int tile = tile0 + tl;

        // h1 = relu(P+Q) -> packed f16 swizzled into sH1
#pragma unroll
        for (int i = 0; i < 4; ++i) {
            short8 hv = h8_add_relu(rp[i], rq[i]);
            int chunk = (q * 4 + i) ^ (le & 7);
            *reinterpret_cast<short8*>(&sH1[le * 128 + chunk * 8]) = hv;
        }

        // prefetch next tile's gather (hidden under GEMM2 + layer3)
        if (tl + 1 < TPB_TILES) {
            int e = (tile + 1) * EPT + le; if (e >= E_TOTAL) e = E_TOTAL - 1;
            int sn = eidx[e], dn = eidx[E_TOTAL + e];
            const unsigned short* ps = PQ + (size_t)sn * 256 + q * 32;
            const unsigned short* pd = PQ + (size_t)dn * 256 + 128 + q * 32;
#pragma unroll
            for (int i = 0; i < 4; ++i) {
                rp[i] = *reinterpret_cast<const short8*>(ps + i * 8);
                rq[i] = *reinterpret_cast<const short8*>(pd + i * 8);
            }
        }
        __syncthreads();   // barrier 1: sH1 ready (tile 0 also: sW2/sB2/sW3)

        // GEMM2 swapped: D[ch][edge] = W2^T @ h1^T; wave w owns edges w*16..w*16+15
        const int hrow = w * 16 + e16;
        f32x4 acc[4];
#pragma unroll
        for (int t = 0; t < 4; ++t) acc[t] = (f32x4){0.f, 0.f, 0.f, 0.f};
#pragma unroll
        for (int ks = 0; ks < 4; ++ks) {
            short8 hb = *reinterpret_cast<const short8*>(
                &sH1[hrow * 128 + (((ks * 4 + g) ^ (hrow & 7)) * 8)]);
#pragma unroll
            for (int t = 0; t < 4; ++t) {
                int ch = t * 16 + e16;
                short8 av = *reinterpret_cast<const short8*>(
                    &sW2[ch * 128 + (((ks * 4 + g) ^ (ch & 7)) * 8)]);
                acc[t] = mfma_f16(av, hb, acc[t]);
            }
        }

        // layer 3: lane holds ch = t*16 + g*4 + rr for edge hrow
        float lg0 = 0.f, lg1 = 0.f;
#pragma unroll
        for (int t = 0; t < 4; ++t) {
            int c0 = t * 16 + g * 4;
            float4 bb  = *reinterpret_cast<const float4*>(&sB2[c0]);
            float4 w30 = *reinterpret_cast<const float4*>(&sW3[c0 * 2]);
            float4 w31 = *reinterpret_cast<const float4*>(&sW3[c0 * 2 + 4]);
            float h0 = fmaxf(acc[t][0] + bb.x, 0.f);
            float h1 = fmaxf(acc[t][1] + bb.y, 0.f);
            float h2 = fmaxf(acc[t][2] + bb.z, 0.f);
            float h3 = fmaxf(acc[t][3] + bb.w, 0.f);
            lg0 = fmaf(h0, w30.x, lg0); lg1 = fmaf(h0, w30.y, lg1);
            lg0 = fmaf(h1, w30.z, lg0); lg1 = fmaf(h1, w30.w, lg1);
            lg0 = fmaf(h2, w31.x, lg0); lg1 = fmaf(h2, w31.y, lg1);
            lg0 = fmaf(h3, w31.z, lg0); lg1 = fmaf(h3, w31.w, lg1);
        }
        // reduce over the 4 k-groups (lanes e16, e16+16, e16+32, e16+48)
        lg0 += __shfl_xor(lg0, 16, 64); lg1 += __shfl_xor(lg1, 16, 64);
        lg0 += __shfl_xor(lg0, 32, 64); lg1 += __shfl_xor(lg1, 32, 64);

        int ge = tile * EPT + hrow;
        if (g == 0 && ge < E_TOTAL) {
            float v0 = lg0 + b3v0, v1 = lg1 + b3v1;
            float m = fmaxf(v0, v1);
            float lse = m + __logf(__expf(v0 - m) + __expf(v1 - m));
            *reinterpret_cast<float2*>(out + (size_t)ge * 2) = make_float2(v0 - lse, v1 - lse);
        }
        __syncthreads();   // barrier 2: sH1 reads done before next tile's overwrite
    }
}

// ============================ HOST ============================

extern "C" void kernel_launch(void* const* d_in, const int* in_sizes, int n_in,
                              void* d_out, int out_size, void* d_ws, size_t ws_size,
                              hipStream_t stream) {
    const float* enc = (const float*)d_in[0];
    const int*   eidx = (const int*)d_in[1];
    const float* W1 = (const float*)d_in[2];
    const float* b1 = (const float*)d_in[3];
    const float* W2 = (const float*)d_in[4];
    const float* b2 = (const float*)d_in[5];
    const float* W3 = (const float*)d_in[6];
    const float* b3 = (const float*)d_in[7];
    float* out = (float*)d_out;

    unsigned short* PQ    = (unsigned short*)d_ws;           // 100000*256 f16 = 51.2 MB
    unsigned short* w1abt = PQ + (size_t)N_NODES * 256;      // 64 KB
    unsigned short* w2t   = w1abt + 256 * 128;               // 16 KB

    prep_w_fast<<<160, 256, 0, stream>>>(W1, W2, w1abt, w2t);
    build_pq<<<(N_NODES + 63) / 64, 256, 0, stream>>>(enc, b1, w1abt, PQ);
    edge_head<<<NB, 512, 0, stream>>>(PQ, eidx, w2t, b2, W3, b3, out);
}